// Round 10
// baseline (429.267 us; speedup 1.0000x reference)
//
#include <hip/hip_runtime.h>
#include <hip/hip_bf16.h>
#include <stdint.h>

// QLSTM: T=256, B=2048, DIN=128, NQ=16, 4 gates. fp32 inputs, fp32 outputs.
// R14: exchange-free lane remap. Wall = 256 x L_chain (serial recurrence); the
// only lever is shortening one step's critical path. Old map (gate,qubit) put
// a cross-lane gate exchange (bpermute ~100cy / permlane tree) inside the
// chain. New map: lane = (batch beta, qubit n), wave owns 4 batches; each lane
// computes ALL 4 gates locally (shared h-rotates, 4 parallel dot/cos/prefix),
// so f,i,g,o are lane-local and c = fmaf(f,c,i*g) needs NO cross-lane op.
// Chain: rot -> fma-chain -> cos -> 4 DPP muls -> exp2/rcp -> c-fma -> tanh -> h.
//   - MFMA tile: rows = 4 timesteps x 4 batches, same kt/hi-lo ladder order
//     -> bit-identical z. 64 tiles of 4 steps.
//   - out stores: lane (beta,n) writes h every step -> 256B/wave coalesced.
//   - W frags in LDS (R9 form), zt per-wave single-buffer, one barrier total.
//   - absmax must stay exactly 0.00390625 (same per-element arithmetic).

#define T_STEPS 256
#define BATCH   2048
#define DIN     128
#define NQ      16
#define DTOT    144
#define NTILE   64          // 64 tiles of 4 timesteps
#define ZROW    70          // padded z row: reads <=3-way, writes 2-way banks

typedef __attribute__((ext_vector_type(8))) short bf16x8;
typedef __attribute__((ext_vector_type(4))) float f32x4;

__device__ __forceinline__ float bf2f(unsigned short u) {
    union { unsigned int i; float f; } v; v.i = ((unsigned int)u) << 16; return v.f;
}
__device__ __forceinline__ unsigned short f2bf(float f) {
    union { float f; unsigned int i; } v; v.f = f;
    unsigned int i = v.i;
    unsigned int r = i + 0x7fffu + ((i >> 16) & 1u);   // round-nearest-even
    return (unsigned short)(r >> 16);
}
__device__ __forceinline__ float ldval(const float* p) { return *p; }
__device__ __forceinline__ float ldval(const unsigned short* p) { return bf2f(*p); }

// ---------------- per-wave dtype detector (bf16=1, fp32=0), wave-uniform ----------------
__device__ __forceinline__ int detect_bf16(const unsigned int* __restrict__ xw, int lane) {
    int cnt = 0;
#pragma unroll
    for (int i = 0; i < 4; ++i) {
        unsigned int w = xw[lane + i * 64];
        unsigned int e = (w >> 7) & 0xFFu;
        cnt += (e >= 100u && e <= 140u) ? 1 : 0;
    }
#pragma unroll
    for (int d = 32; d > 0; d >>= 1) cnt += __shfl_down(cnt, d, 64);
    int tot = __shfl(cnt, 0, 64);
    return (tot >= 140) ? 1 : 0;
}

// ---------------- DPP helpers ----------------
template <int CTRL>
__device__ __forceinline__ float dpp_sh(float v) {   // shift w/ multiplicative identity
    int r = __builtin_amdgcn_update_dpp(__builtin_bit_cast(int, 1.0f),
                                        __builtin_bit_cast(int, v),
                                        CTRL, 0xF, 0xF, false);
    return __builtin_bit_cast(float, r);
}
template <int CTRL>
__device__ __forceinline__ float rot16(float v) {    // row rotate (pure VALU)
    int r = __builtin_amdgcn_update_dpp(0, __builtin_bit_cast(int, v),
                                        CTRL, 0xF, 0xF, false);
    return __builtin_bit_cast(float, r);
}

// ---------------- cos + inclusive row-prefix product ----------------
template <int BASE>
__device__ __forceinline__ float cosprefix(float z) {
    float cz = __cosf(z);
    cz *= dpp_sh<BASE + 1>(cz);
    cz *= dpp_sh<BASE + 2>(cz);
    cz *= dpp_sh<BASE + 4>(cz);
    cz *= dpp_sh<BASE + 8>(cz);
    return cz;
}

__device__ __forceinline__ float sigm_(float a) {
    float e = __builtin_amdgcn_exp2f(a * -1.442695041f);
    return __builtin_amdgcn_rcpf(1.f + e);
}
__device__ __forceinline__ float tanh_(float a) {
    float e = __builtin_amdgcn_exp2f(a * -2.885390082f);
    return fmaf(2.f, __builtin_amdgcn_rcpf(1.f + e), -1.f);
}

// ---------------- one step, all 4 gates lane-local ----------------
template <int BASE>
__device__ __forceinline__ void qstep4(int t, int b, int n,
                                       float zb0, float zb1, float zb2, float zb3,
                                       const float (&Wp)[4][16], float& h, float& c,
                                       float* __restrict__ out)
{
    // shared h-rotates (gate-independent)
    float h1  = rot16<0x121>(h), h2  = rot16<0x122>(h), h3  = rot16<0x123>(h);
    float h4  = rot16<0x124>(h), h5  = rot16<0x125>(h), h6  = rot16<0x126>(h), h7  = rot16<0x127>(h);
    float h8  = rot16<0x128>(h), h9  = rot16<0x129>(h), h10 = rot16<0x12A>(h), h11 = rot16<0x12B>(h);
    float h12 = rot16<0x12C>(h), h13 = rot16<0x12D>(h), h14 = rot16<0x12E>(h), h15 = rot16<0x12F>(h);

    float zin[4] = {zb0, zb1, zb2, zb3};
    float cz[4];
#pragma unroll
    for (int g = 0; g < 4; ++g) {
        float a0 = fmaf(Wp[g][3],  h3,  fmaf(Wp[g][2],  h2,  fmaf(Wp[g][1],  h1,  fmaf(Wp[g][0], h, zin[g]))));
        float a1 = fmaf(Wp[g][7],  h7,  fmaf(Wp[g][6],  h6,  fmaf(Wp[g][5],  h5,  Wp[g][4]  * h4)));
        float a2 = fmaf(Wp[g][11], h11, fmaf(Wp[g][10], h10, fmaf(Wp[g][9],  h9,  Wp[g][8]  * h8)));
        float a3 = fmaf(Wp[g][15], h15, fmaf(Wp[g][14], h14, fmaf(Wp[g][13], h13, Wp[g][12] * h12)));
        cz[g] = cosprefix<BASE>((a0 + a1) + (a2 + a3));
    }

    float fv = sigm_(cz[0]);
    float iv = sigm_(cz[1]);
    float gv = tanh_(cz[2]);
    float ov = sigm_(cz[3]);

    c = fmaf(fv, c, iv * gv);
    float tc = tanh_(c);
    h = ov * tc;

    out[(size_t)t * (BATCH * NQ) + (size_t)b * NQ + n] = h;
}

// ---------------- fused per-wave main (4 batches / wave, exchange-free) ----------------
template <int BASE, typename InT>
__device__ __forceinline__ void fused_main(
    const InT* __restrict__ x, const InT* __restrict__ W,
    const InT* __restrict__ bv, const InT* __restrict__ th,
    float* __restrict__ out, int bA, int w, int lane,
    const float (&Wp)[4][16], float (*zt)[ZROW],
    bf16x8 (*wfh)[64], bf16x8 (*wfl)[64])
{
    const int m = lane & 15, quad = lane >> 4;
    const int beta = quad, n = m;
    const int b = bA + beta;

    // ---- cooperative W-fragment build: wave w handles k-tiles 2w, 2w+1 ----
#pragma unroll
    for (int kk = 0; kk < 2; ++kk) {
        const int kt = 2 * w + kk;
        if constexpr (sizeof(InT) == 2) {
#pragma unroll
            for (int nb = 0; nb < 4; ++nb)
                wfh[kt * 4 + nb][lane] = *(const bf16x8*)((const unsigned short*)W +
                                         (size_t)(nb * 16 + m) * DTOT + kt * 32 + quad * 8);
        } else {
#pragma unroll
            for (int nb = 0; nb < 4; ++nb) {
                const float* p = (const float*)W + (size_t)(nb * 16 + m) * DTOT + kt * 32 + quad * 8;
                bf16x8 ah, al;
#pragma unroll
                for (int j = 0; j < 8; ++j) {
                    float wv = p[j];
                    unsigned short hh = f2bf(wv);
                    ah[j] = (short)hh;
                    al[j] = (short)f2bf(wv - bf2f(hh));
                }
                wfh[kt * 4 + nb][lane] = ah;
                wfl[kt * 4 + nb][lane] = al;
            }
        }
    }
    float bias[4];
#pragma unroll
    for (int g = 0; g < 4; ++g)
        bias[g] = ldval(bv + g * 16 + n) + ldval(th + g * 16 + n);
    __syncthreads();            // the ONLY barrier; wf* read-only afterwards

    // A-row m -> x row (t = tl*4 + (m>>2), batch = bA + (m&3))
    const InT* xbase = x + ((size_t)(m >> 2) * BATCH + (size_t)(bA + (m & 3))) * DIN + quad * 8;

    f32x4 rx[8]; bf16x8 rbx[4];
    auto LOAD = [&](int tl) {
        const InT* p = xbase + (size_t)tl * ((size_t)4 * BATCH * DIN);
#pragma unroll
        for (int kt = 0; kt < 4; ++kt) {
            if constexpr (sizeof(InT) == 2) {
                rbx[kt] = *(const bf16x8*)(p + kt * 32);
            } else {
                rx[2 * kt]     = *(const f32x4*)((const float*)p + kt * 32);
                rx[2 * kt + 1] = *(const f32x4*)((const float*)p + kt * 32 + 4);
            }
        }
    };
    auto PRODUCE = [&]() {
        f32x4 acc[4] = {};
#pragma unroll
        for (int kt = 0; kt < 4; ++kt) {
            if constexpr (sizeof(InT) == 2) {
#pragma unroll
                for (int nb = 0; nb < 4; ++nb)
                    acc[nb] = __builtin_amdgcn_mfma_f32_16x16x32_bf16(rbx[kt], wfh[kt * 4 + nb][lane], acc[nb], 0, 0, 0);
            } else {
                bf16x8 ah, al;
#pragma unroll
                for (int j = 0; j < 8; ++j) {
                    float xv = rx[2 * kt + (j >> 2)][j & 3];
                    unsigned short hh = f2bf(xv);
                    ah[j] = (short)hh;
                    al[j] = (short)f2bf(xv - bf2f(hh));
                }
#pragma unroll
                for (int nb = 0; nb < 4; ++nb)
                    acc[nb] = __builtin_amdgcn_mfma_f32_16x16x32_bf16(ah, wfh[kt * 4 + nb][lane], acc[nb], 0, 0, 0);
#pragma unroll
                for (int nb = 0; nb < 4; ++nb)
                    acc[nb] = __builtin_amdgcn_mfma_f32_16x16x32_bf16(al, wfh[kt * 4 + nb][lane], acc[nb], 0, 0, 0);
#pragma unroll
                for (int nb = 0; nb < 4; ++nb)
                    acc[nb] = __builtin_amdgcn_mfma_f32_16x16x32_bf16(ah, wfl[kt * 4 + nb][lane], acc[nb], 0, 0, 0);
            }
        }
        // C row i = quad*4+r  <->  (t_local = i>>2, batch = i&3); col = nb*16+m
#pragma unroll
        for (int nb = 0; nb < 4; ++nb)
#pragma unroll
            for (int r = 0; r < 4; ++r)
                zt[quad * 4 + r][nb * 16 + m] = acc[nb][r];
    };

    float h = 0.f, c = 0.f;

    LOAD(0);
    PRODUCE();
    LOAD(1);

#pragma unroll 1
    for (int tl = 0; tl < NTILE; ++tl) {
        float zr[16];
#pragma unroll
        for (int tt = 0; tt < 4; ++tt)
#pragma unroll
            for (int g = 0; g < 4; ++g)
                zr[tt * 4 + g] = zt[tt * 4 + beta][g * 16 + n] + bias[g];   // drain before overwrite
        if (tl < NTILE - 1) PRODUCE();
        if (tl < NTILE - 2) LOAD(tl + 2);
#pragma unroll
        for (int tt = 0; tt < 4; ++tt)
            qstep4<BASE>(tl * 4 + tt, b, n,
                         zr[tt * 4 + 0], zr[tt * 4 + 1], zr[tt * 4 + 2], zr[tt * 4 + 3],
                         Wp, h, c, out);
    }

    out[(size_t)T_STEPS * BATCH * NQ + (size_t)b * NQ + n] = h;                       // hx
    out[(size_t)T_STEPS * BATCH * NQ + (size_t)BATCH * NQ + (size_t)b * NQ + n] = c;  // cx
}

__global__ __launch_bounds__(128, 1) void qlstm_fused(
    const void* __restrict__ x_, const void* __restrict__ W_,
    const void* __restrict__ b_, const void* __restrict__ th_,
    float* __restrict__ out)
{
    __shared__ float  zw[2][16][ZROW];      // 8.75 KiB: per-wave z tiles
    __shared__ bf16x8 wfh[16][64];          // 16 KiB: W hi fragments (shared)
    __shared__ bf16x8 wfl[16][64];          // 16 KiB: W lo fragments (fp32 path)

    const int lane = threadIdx.x & 63;
    const int w    = threadIdx.x >> 6;      // 0..1
    const int bA   = (blockIdx.x * 2 + w) * 4;
    const int n    = lane & 15;

    const int isbf = __builtin_amdgcn_readfirstlane(detect_bf16((const unsigned int*)x_, lane));

    // runtime probe of DPP row_ror direction (wave-uniform)
    int pr  = __builtin_amdgcn_update_dpp(0, lane, 0x121, 0xF, 0xF, false);
    int p0r = __shfl(pr, 0, 64);
    const int d = (p0r == 1) ? 1 : 15;

    float Wp[4][16];
    if (isbf) {
        const unsigned short* W = (const unsigned short*)W_;
#pragma unroll
        for (int g = 0; g < 4; ++g)
#pragma unroll
            for (int k = 0; k < 16; ++k)
                Wp[g][k] = bf2f(W[(size_t)(g * 16 + n) * DTOT + DIN + ((n + k * d) & 15)]);
    } else {
        const float* W = (const float*)W_;
#pragma unroll
        for (int g = 0; g < 4; ++g)
#pragma unroll
            for (int k = 0; k < 16; ++k)
                Wp[g][k] = W[(size_t)(g * 16 + n) * DTOT + DIN + ((n + k * d) & 15)];
    }

    // runtime probe of DPP row_shr direction (wave-uniform) for the prefix product
    int probe = __builtin_amdgcn_update_dpp(999, lane, 0x111, 0xF, 0xF, false);
    int p2 = __shfl(probe, 2, 64);

    if (isbf) {
        if (p2 == 1) fused_main<0x110, unsigned short>((const unsigned short*)x_, (const unsigned short*)W_,
                                                       (const unsigned short*)b_, (const unsigned short*)th_,
                                                       out, bA, w, lane, Wp, zw[w], wfh, wfl);
        else         fused_main<0x100, unsigned short>((const unsigned short*)x_, (const unsigned short*)W_,
                                                       (const unsigned short*)b_, (const unsigned short*)th_,
                                                       out, bA, w, lane, Wp, zw[w], wfh, wfl);
    } else {
        if (p2 == 1) fused_main<0x110, float>((const float*)x_, (const float*)W_,
                                              (const float*)b_, (const float*)th_,
                                              out, bA, w, lane, Wp, zw[w], wfh, wfl);
        else         fused_main<0x100, float>((const float*)x_, (const float*)W_,
                                              (const float*)b_, (const float*)th_,
                                              out, bA, w, lane, Wp, zw[w], wfh, wfl);
    }
}

extern "C" void kernel_launch(void* const* d_in, const int* in_sizes, int n_in,
                              void* d_out, int out_size, void* d_ws, size_t ws_size,
                              hipStream_t stream) {
    const void* x  = d_in[0];
    const void* W  = d_in[1];
    const void* bv = d_in[2];
    const void* th = d_in[3];
    (void)d_ws; (void)ws_size;
    qlstm_fused<<<BATCH / 8, 128, 0, stream>>>(x, W, bv, th, (float*)d_out);
}

// Round 11
// 387.447 us; speedup vs baseline: 1.1079x; 1.1079x over previous
//
#include <hip/hip_runtime.h>
#include <hip/hip_bf16.h>
#include <stdint.h>

// QLSTM: T=256, B=2048, DIN=128, NQ=16, 4 gates. fp32 inputs, fp32 outputs.
// R15: R10 (best measured: asm dot+prefix, 1 batch/wave, 2 waves/SIMD) with the
// two fattest per-step blocks slimmed:
//   (a) gate exchange: permlane tree (3 swaps + 11 selects, ~17 inst) -> 4x
//       ds_bpermute (exact data movement; LDS latency covered by the
//       co-resident wave, which R13's 1-wave config lacked).
//   (b) gate nonlinearity: g==2 branches folded to per-lane constants
//       s = fmaf(ksc, rcp(1+exp2(cz*kexp)), koff) (bit-compatible, validated
//       in R11-R13). tanh tail same folded form.
// Everything else byte-for-byte R10: W frags in LDS, single-buffer z tile,
// one barrier, asm-fused dot (17 inst), asm prefix with s_nop guards.
// Model: scan is ISSUE-bound (~512 wave-steps/SIMD); each inst removed/step
// saves ~0.4us. absmax must stay exactly 0.00390625.

#define T_STEPS 256
#define BATCH   2048
#define DIN     128
#define NQ      16
#define DTOT    144
#define NTILE   16          // 16 tiles of 16 timesteps
#define ZROW    66          // padded z row (floats): 4*ZROW%32=8 -> conflict-free

typedef __attribute__((ext_vector_type(8))) short bf16x8;
typedef __attribute__((ext_vector_type(4))) float f32x4;

__device__ __forceinline__ float bf2f(unsigned short u) {
    union { unsigned int i; float f; } v; v.i = ((unsigned int)u) << 16; return v.f;
}
__device__ __forceinline__ unsigned short f2bf(float f) {
    union { float f; unsigned int i; } v; v.f = f;
    unsigned int i = v.i;
    unsigned int r = i + 0x7fffu + ((i >> 16) & 1u);   // round-nearest-even
    return (unsigned short)(r >> 16);
}
__device__ __forceinline__ float ldval(const float* p) { return *p; }
__device__ __forceinline__ float ldval(const unsigned short* p) { return bf2f(*p); }

// ---------------- per-wave dtype detector (bf16=1, fp32=0), wave-uniform ----------------
__device__ __forceinline__ int detect_bf16(const unsigned int* __restrict__ xw, int lane) {
    int cnt = 0;
#pragma unroll
    for (int i = 0; i < 4; ++i) {
        unsigned int w = xw[lane + i * 64];
        unsigned int e = (w >> 7) & 0xFFu;
        cnt += (e >= 100u && e <= 140u) ? 1 : 0;
    }
#pragma unroll
    for (int d = 32; d > 0; d >>= 1) cnt += __shfl_down(cnt, d, 64);
    int tot = __shfl(cnt, 0, 64);
    return (tot >= 140) ? 1 : 0;
}

// ---------------- one recurrence step ----------------
template <int BASE>
__device__ __forceinline__ void qstep(int t, int g, int n, float cur,
                                      const float (&Wp)[16], float& h, float& c,
                                      float& hsave, float* __restrict__ out, int b,
                                      float kexp, float ksc, float koff,
                                      int a_f, int a_i, int a_g, int a_o)
{
    // h-dot: rotate fused into fmac via DPP. 4 chains interleaved 4-apart so
    // no accumulator is touched by consecutive instructions.
    float a0 = cur, a1, a2, a3;
    asm volatile(
        "s_nop 1\n\t"
        "v_fmac_f32 %0, %4, %5\n\t"
        "v_mul_f32_dpp %1, %4, %6 row_ror:4 row_mask:0xf bank_mask:0xf\n\t"
        "v_mul_f32_dpp %2, %4, %7 row_ror:8 row_mask:0xf bank_mask:0xf\n\t"
        "v_mul_f32_dpp %3, %4, %8 row_ror:12 row_mask:0xf bank_mask:0xf\n\t"
        "v_fmac_f32_dpp %0, %4, %9 row_ror:1 row_mask:0xf bank_mask:0xf\n\t"
        "v_fmac_f32_dpp %1, %4, %10 row_ror:5 row_mask:0xf bank_mask:0xf\n\t"
        "v_fmac_f32_dpp %2, %4, %11 row_ror:9 row_mask:0xf bank_mask:0xf\n\t"
        "v_fmac_f32_dpp %3, %4, %12 row_ror:13 row_mask:0xf bank_mask:0xf\n\t"
        "v_fmac_f32_dpp %0, %4, %13 row_ror:2 row_mask:0xf bank_mask:0xf\n\t"
        "v_fmac_f32_dpp %1, %4, %14 row_ror:6 row_mask:0xf bank_mask:0xf\n\t"
        "v_fmac_f32_dpp %2, %4, %15 row_ror:10 row_mask:0xf bank_mask:0xf\n\t"
        "v_fmac_f32_dpp %3, %4, %16 row_ror:14 row_mask:0xf bank_mask:0xf\n\t"
        "v_fmac_f32_dpp %0, %4, %17 row_ror:3 row_mask:0xf bank_mask:0xf\n\t"
        "v_fmac_f32_dpp %1, %4, %18 row_ror:7 row_mask:0xf bank_mask:0xf\n\t"
        "v_fmac_f32_dpp %2, %4, %19 row_ror:11 row_mask:0xf bank_mask:0xf\n\t"
        "v_fmac_f32_dpp %3, %4, %20 row_ror:15 row_mask:0xf bank_mask:0xf"
        : "+v"(a0), "=&v"(a1), "=&v"(a2), "=&v"(a3)
        : "v"(h), "v"(Wp[0]), "v"(Wp[4]), "v"(Wp[8]), "v"(Wp[12]),
          "v"(Wp[1]), "v"(Wp[5]), "v"(Wp[9]), "v"(Wp[13]),
          "v"(Wp[2]), "v"(Wp[6]), "v"(Wp[10]), "v"(Wp[14]),
          "v"(Wp[3]), "v"(Wp[7]), "v"(Wp[11]), "v"(Wp[15]));
    float z = (a0 + a1) + (a2 + a3);

    float cz = __cosf(z);
    // inclusive prefix product, in-place DPP Hillis-Steele: invalid lanes keep
    // dst (BC=0) = multiplicative identity. s_nop 1 between dependent stages.
    if constexpr (BASE == 0x110) {
        asm volatile(
            "s_nop 1\n\t"
            "v_mul_f32_dpp %0, %0, %0 row_shr:1 row_mask:0xf bank_mask:0xf\n\t"
            "s_nop 1\n\t"
            "v_mul_f32_dpp %0, %0, %0 row_shr:2 row_mask:0xf bank_mask:0xf\n\t"
            "s_nop 1\n\t"
            "v_mul_f32_dpp %0, %0, %0 row_shr:4 row_mask:0xf bank_mask:0xf\n\t"
            "s_nop 1\n\t"
            "v_mul_f32_dpp %0, %0, %0 row_shr:8 row_mask:0xf bank_mask:0xf"
            : "+v"(cz));
    } else {
        asm volatile(
            "s_nop 1\n\t"
            "v_mul_f32_dpp %0, %0, %0 row_shl:1 row_mask:0xf bank_mask:0xf\n\t"
            "s_nop 1\n\t"
            "v_mul_f32_dpp %0, %0, %0 row_shl:2 row_mask:0xf bank_mask:0xf\n\t"
            "s_nop 1\n\t"
            "v_mul_f32_dpp %0, %0, %0 row_shl:4 row_mask:0xf bank_mask:0xf\n\t"
            "s_nop 1\n\t"
            "v_mul_f32_dpp %0, %0, %0 row_shl:8 row_mask:0xf bank_mask:0xf"
            : "+v"(cz));
    }

    // gate nonlinearity, folded: s = fmaf(ksc, 1/(1+2^(cz*kexp)), koff)
    float e = __builtin_amdgcn_exp2f(cz * kexp);
    float rr = __builtin_amdgcn_rcpf(1.f + e);
    float s = fmaf(ksc, rr, koff);

    // gate exchange: 4x ds_bpermute (exact; latency covered by co-resident wave)
    int si = __builtin_bit_cast(int, s);
    float fv = __builtin_bit_cast(float, __builtin_amdgcn_ds_bpermute(a_f, si));
    float iv = __builtin_bit_cast(float, __builtin_amdgcn_ds_bpermute(a_i, si));
    float gv = __builtin_bit_cast(float, __builtin_amdgcn_ds_bpermute(a_g, si));
    float ov = __builtin_bit_cast(float, __builtin_amdgcn_ds_bpermute(a_o, si));

    c = fmaf(fv, c, iv * gv);
    float e2 = __builtin_amdgcn_exp2f(c * -2.885390082f);
    float tc = fmaf(2.f, __builtin_amdgcn_rcpf(1.f + e2), -1.f);
    h = ov * tc;

    if ((t & 3) == g) hsave = h;
    if ((t & 3) == 3)
        out[(size_t)(t - 3 + g) * (BATCH * NQ) + (size_t)b * NQ + n] = hsave;
}

// ---------------- fused per-wave main ----------------
// wfh/wfl[kt*4+nb][lane]: W MFMA fragments, block-shared, built once.
// zt[16][ZROW]: per-wave private z tile (single buffer).
template <int BASE, typename InT>
__device__ __forceinline__ void fused_main(
    const InT* __restrict__ x, const InT* __restrict__ W,
    const InT* __restrict__ bv, const InT* __restrict__ th,
    float* __restrict__ out, int b, int w, int lane,
    const float (&Wp)[16], float (*zt)[ZROW],
    bf16x8 (*wfh)[64], bf16x8 (*wfl)[64])
{
    const int m = lane & 15, quad = lane >> 4;
    const int g = quad, n = m;
    const float kexp = (g == 2) ? -2.885390082f : -1.442695041f;
    const float ksc  = (g == 2) ? 2.f : 1.f;
    const float koff = (g == 2) ? -1.f : 0.f;
    const int a_f = n << 2, a_i = (16 + n) << 2, a_g = (32 + n) << 2, a_o = (48 + n) << 2;

    // ---- cooperative W-fragment build: wave w handles k-tile kt = w ----
    if constexpr (sizeof(InT) == 2) {
#pragma unroll
        for (int nb = 0; nb < 4; ++nb)
            wfh[w * 4 + nb][lane] = *(const bf16x8*)((const unsigned short*)W +
                                    (size_t)(nb * 16 + m) * DTOT + w * 32 + quad * 8);
    } else {
#pragma unroll
        for (int nb = 0; nb < 4; ++nb) {
            const float* p = (const float*)W + (size_t)(nb * 16 + m) * DTOT + w * 32 + quad * 8;
            bf16x8 ah, al;
#pragma unroll
            for (int j = 0; j < 8; ++j) {
                float wv = p[j];
                unsigned short hh = f2bf(wv);
                ah[j] = (short)hh;
                al[j] = (short)f2bf(wv - bf2f(hh));
            }
            wfh[w * 4 + nb][lane] = ah;
            wfl[w * 4 + nb][lane] = al;
        }
    }
    const float bias = ldval(bv + lane) + ldval(th + lane);
    __syncthreads();            // the ONLY barrier; wf* read-only afterwards

    // A-rows for tile tl: timesteps tl*16 + m of batch b.
    const InT* xbase = x + ((size_t)m * BATCH + (size_t)b) * DIN + quad * 8;

    f32x4 rx[8]; bf16x8 rbx[4];
    auto LOAD = [&](int tl) {
        const InT* p = xbase + (size_t)tl * ((size_t)16 * BATCH * DIN);
#pragma unroll
        for (int kt = 0; kt < 4; ++kt) {
            if constexpr (sizeof(InT) == 2) {
                rbx[kt] = *(const bf16x8*)(p + kt * 32);
            } else {
                rx[2 * kt]     = *(const f32x4*)((const float*)p + kt * 32);
                rx[2 * kt + 1] = *(const f32x4*)((const float*)p + kt * 32 + 4);
            }
        }
    };
    auto PRODUCE = [&]() {
        f32x4 acc[4] = {};
#pragma unroll
        for (int kt = 0; kt < 4; ++kt) {
            if constexpr (sizeof(InT) == 2) {
#pragma unroll
                for (int nb = 0; nb < 4; ++nb)
                    acc[nb] = __builtin_amdgcn_mfma_f32_16x16x32_bf16(rbx[kt], wfh[kt * 4 + nb][lane], acc[nb], 0, 0, 0);
            } else {
                bf16x8 ah, al;
#pragma unroll
                for (int j = 0; j < 8; ++j) {
                    float xv = rx[2 * kt + (j >> 2)][j & 3];
                    unsigned short hh = f2bf(xv);
                    ah[j] = (short)hh;
                    al[j] = (short)f2bf(xv - bf2f(hh));
                }
#pragma unroll
                for (int nb = 0; nb < 4; ++nb)
                    acc[nb] = __builtin_amdgcn_mfma_f32_16x16x32_bf16(ah, wfh[kt * 4 + nb][lane], acc[nb], 0, 0, 0);
#pragma unroll
                for (int nb = 0; nb < 4; ++nb)
                    acc[nb] = __builtin_amdgcn_mfma_f32_16x16x32_bf16(al, wfh[kt * 4 + nb][lane], acc[nb], 0, 0, 0);
#pragma unroll
                for (int nb = 0; nb < 4; ++nb)
                    acc[nb] = __builtin_amdgcn_mfma_f32_16x16x32_bf16(ah, wfl[kt * 4 + nb][lane], acc[nb], 0, 0, 0);
            }
        }
        // z[t = quad*4+r][col = nb*16+m]; banks (8*quad + m) % 32 -> conflict-free
#pragma unroll
        for (int nb = 0; nb < 4; ++nb)
#pragma unroll
            for (int r = 0; r < 4; ++r)
                zt[quad * 4 + r][nb * 16 + m] = acc[nb][r];
    };

    float h = 0.f, c = 0.f, hsave = 0.f;

    LOAD(0);
    PRODUCE();
    LOAD(1);

#pragma unroll 1
    for (int tl = 0; tl < NTILE; ++tl) {
        const int t0 = tl * 16;
        float zr[16];
#pragma unroll
        for (int j = 0; j < 16; ++j) zr[j] = zt[j][lane] + bias;   // drain before overwrite
        if (tl < NTILE - 1) PRODUCE();
        if (tl < NTILE - 2) LOAD(tl + 2);
#pragma unroll
        for (int j = 0; j < 16; ++j)
            qstep<BASE>(t0 + j, g, n, zr[j], Wp, h, c, hsave, out, b,
                        kexp, ksc, koff, a_f, a_i, a_g, a_o);
    }

    if (g == 0) {
        out[(size_t)T_STEPS * BATCH * NQ + (size_t)b * NQ + n] = h;                       // hx
        out[(size_t)T_STEPS * BATCH * NQ + (size_t)BATCH * NQ + (size_t)b * NQ + n] = c;  // cx
    }
}

__global__ __launch_bounds__(256, 2) void qlstm_fused(
    const void* __restrict__ x_, const void* __restrict__ W_,
    const void* __restrict__ b_, const void* __restrict__ th_,
    float* __restrict__ out)
{
    __shared__ float  zw[4][NTILE][ZROW];   // 16.5 KiB: per-wave z tiles
    __shared__ bf16x8 wfh[16][64];          // 16 KiB: W hi fragments (shared)
    __shared__ bf16x8 wfl[16][64];          // 16 KiB: W lo fragments (fp32 path)

    const int lane = threadIdx.x & 63;
    const int w    = threadIdx.x >> 6;
    const int b    = blockIdx.x * 4 + w;
    const int n    = lane & 15;

    const int isbf = __builtin_amdgcn_readfirstlane(detect_bf16((const unsigned int*)x_, lane));

    // runtime probe of DPP row_ror direction (wave-uniform)
    int pr  = __builtin_amdgcn_update_dpp(0, lane, 0x121, 0xF, 0xF, false);
    int p0r = __shfl(pr, 0, 64);
    const int d = (p0r == 1) ? 1 : 15;

    float Wp[16];
    if (isbf) {
        const unsigned short* W = (const unsigned short*)W_;
#pragma unroll
        for (int k = 0; k < 16; ++k)
            Wp[k] = bf2f(W[(size_t)lane * DTOT + DIN + ((n + k * d) & 15)]);
    } else {
        const float* W = (const float*)W_;
#pragma unroll
        for (int k = 0; k < 16; ++k)
            Wp[k] = W[(size_t)lane * DTOT + DIN + ((n + k * d) & 15)];
    }

    // runtime probe of DPP row_shr direction (wave-uniform) for the prefix product
    int probe = __builtin_amdgcn_update_dpp(999, lane, 0x111, 0xF, 0xF, false);
    int p2 = __shfl(probe, 2, 64);

    if (isbf) {
        if (p2 == 1) fused_main<0x110, unsigned short>((const unsigned short*)x_, (const unsigned short*)W_,
                                                       (const unsigned short*)b_, (const unsigned short*)th_,
                                                       out, b, w, lane, Wp, zw[w], wfh, wfl);
        else         fused_main<0x100, unsigned short>((const unsigned short*)x_, (const unsigned short*)W_,
                                                       (const unsigned short*)b_, (const unsigned short*)th_,
                                                       out, b, w, lane, Wp, zw[w], wfh, wfl);
    } else {
        if (p2 == 1) fused_main<0x110, float>((const float*)x_, (const float*)W_,
                                              (const float*)b_, (const float*)th_,
                                              out, b, w, lane, Wp, zw[w], wfh, wfl);
        else         fused_main<0x100, float>((const float*)x_, (const float*)W_,
                                              (const float*)b_, (const float*)th_,
                                              out, b, w, lane, Wp, zw[w], wfh, wfl);
    }
}

extern "C" void kernel_launch(void* const* d_in, const int* in_sizes, int n_in,
                              void* d_out, int out_size, void* d_ws, size_t ws_size,
                              hipStream_t stream) {
    const void* x  = d_in[0];
    const void* W  = d_in[1];
    const void* bv = d_in[2];
    const void* th = d_in[3];
    (void)d_ws; (void)ws_size;
    qlstm_fused<<<BATCH / 4, 256, 0, stream>>>(x, W, bv, th, (float*)d_out);
}

// Round 12
// 378.091 us; speedup vs baseline: 1.1354x; 1.0247x over previous
//
#include <hip/hip_runtime.h>
#include <hip/hip_bf16.h>
#include <stdint.h>

// QLSTM: T=256, B=2048, DIN=128, NQ=16, 4 gates. fp32 inputs, fp32 outputs.
// R16: R11 (best measured, 385.1us: 2 interleaved chains/wave, combined asm
// dot + prefix) with the gate exchange switched from the permlane tree
// (2 x ~20 inst per step-pair) to 4x ds_bpermute per chain (8 inst + waits).
// Rationale: R15 proved bpermute==permlane at 2 waves/SIMD; in R11's
// 1-wave/2-chain config the OTHER chain's instructions cover the LDS round
// trip, and the swap removes ~32 inst/step-pair. Everything else is
// byte-for-byte R11. absmax must stay exactly 0.00390625.

#define T_STEPS 256
#define BATCH   2048
#define DIN     128
#define NQ      16
#define DTOT    144
#define NTILE   32          // 32 tiles of 8 timesteps
#define ZROW    66          // padded z row (floats)

typedef __attribute__((ext_vector_type(8))) short bf16x8;
typedef __attribute__((ext_vector_type(4))) float f32x4;

__device__ __forceinline__ float bf2f(unsigned short u) {
    union { unsigned int i; float f; } v; v.i = ((unsigned int)u) << 16; return v.f;
}
__device__ __forceinline__ unsigned short f2bf(float f) {
    union { float f; unsigned int i; } v; v.f = f;
    unsigned int i = v.i;
    unsigned int r = i + 0x7fffu + ((i >> 16) & 1u);   // round-nearest-even
    return (unsigned short)(r >> 16);
}
__device__ __forceinline__ float ldval(const float* p) { return *p; }
__device__ __forceinline__ float ldval(const unsigned short* p) { return bf2f(*p); }

// ---------------- per-wave dtype detector (bf16=1, fp32=0), wave-uniform ----------------
__device__ __forceinline__ int detect_bf16(const unsigned int* __restrict__ xw, int lane) {
    int cnt = 0;
#pragma unroll
    for (int i = 0; i < 4; ++i) {
        unsigned int w = xw[lane + i * 64];
        unsigned int e = (w >> 7) & 0xFFu;
        cnt += (e >= 100u && e <= 140u) ? 1 : 0;
    }
#pragma unroll
    for (int d = 32; d > 0; d >>= 1) cnt += __shfl_down(cnt, d, 64);
    int tot = __shfl(cnt, 0, 64);
    return (tot >= 140) ? 1 : 0;
}

// ---------------- gate exchange: s(row g) -> f/i/g/o at qubit n (exact) ----------------
__device__ __forceinline__ void gex(float s,
                                    int a_f, int a_i, int a_g, int a_o,
                                    float& fv, float& iv, float& gv, float& ov)
{
    int si = __builtin_bit_cast(int, s);
    fv = __builtin_bit_cast(float, __builtin_amdgcn_ds_bpermute(a_f, si));
    iv = __builtin_bit_cast(float, __builtin_amdgcn_ds_bpermute(a_i, si));
    gv = __builtin_bit_cast(float, __builtin_amdgcn_ds_bpermute(a_g, si));
    ov = __builtin_bit_cast(float, __builtin_amdgcn_ds_bpermute(a_o, si));
}

// ---------------- one recurrence step for TWO batches ----------------
template <int BASE>
__device__ __forceinline__ void qstep2(int t, int g, int n,
                                       float curA, float curB, const float (&Wp)[16],
                                       float& hA, float& cA, float& hsA, int bA,
                                       float& hB, float& cB, float& hsB, int bB,
                                       float kexp, float ksc, float koff,
                                       int a_f, int a_i, int a_g, int a_o,
                                       float* __restrict__ out)
{
    // combined h-dot: A/B chains interleaved; accumulator reuse distance 8 inst.
    float a0A = curA, a1A, a2A, a3A;
    float a0B = curB, a1B, a2B, a3B;
    asm volatile(
        "s_nop 1\n\t"
        "v_fmac_f32 %0, %8, %10\n\t"
        "v_fmac_f32 %4, %9, %10\n\t"
        "v_mul_f32_dpp %1, %8, %11 row_ror:4 row_mask:0xf bank_mask:0xf\n\t"
        "v_mul_f32_dpp %5, %9, %11 row_ror:4 row_mask:0xf bank_mask:0xf\n\t"
        "v_mul_f32_dpp %2, %8, %12 row_ror:8 row_mask:0xf bank_mask:0xf\n\t"
        "v_mul_f32_dpp %6, %9, %12 row_ror:8 row_mask:0xf bank_mask:0xf\n\t"
        "v_mul_f32_dpp %3, %8, %13 row_ror:12 row_mask:0xf bank_mask:0xf\n\t"
        "v_mul_f32_dpp %7, %9, %13 row_ror:12 row_mask:0xf bank_mask:0xf\n\t"
        "v_fmac_f32_dpp %0, %8, %14 row_ror:1 row_mask:0xf bank_mask:0xf\n\t"
        "v_fmac_f32_dpp %4, %9, %14 row_ror:1 row_mask:0xf bank_mask:0xf\n\t"
        "v_fmac_f32_dpp %1, %8, %15 row_ror:5 row_mask:0xf bank_mask:0xf\n\t"
        "v_fmac_f32_dpp %5, %9, %15 row_ror:5 row_mask:0xf bank_mask:0xf\n\t"
        "v_fmac_f32_dpp %2, %8, %16 row_ror:9 row_mask:0xf bank_mask:0xf\n\t"
        "v_fmac_f32_dpp %6, %9, %16 row_ror:9 row_mask:0xf bank_mask:0xf\n\t"
        "v_fmac_f32_dpp %3, %8, %17 row_ror:13 row_mask:0xf bank_mask:0xf\n\t"
        "v_fmac_f32_dpp %7, %9, %17 row_ror:13 row_mask:0xf bank_mask:0xf\n\t"
        "v_fmac_f32_dpp %0, %8, %18 row_ror:2 row_mask:0xf bank_mask:0xf\n\t"
        "v_fmac_f32_dpp %4, %9, %18 row_ror:2 row_mask:0xf bank_mask:0xf\n\t"
        "v_fmac_f32_dpp %1, %8, %19 row_ror:6 row_mask:0xf bank_mask:0xf\n\t"
        "v_fmac_f32_dpp %5, %9, %19 row_ror:6 row_mask:0xf bank_mask:0xf\n\t"
        "v_fmac_f32_dpp %2, %8, %20 row_ror:10 row_mask:0xf bank_mask:0xf\n\t"
        "v_fmac_f32_dpp %6, %9, %20 row_ror:10 row_mask:0xf bank_mask:0xf\n\t"
        "v_fmac_f32_dpp %3, %8, %21 row_ror:14 row_mask:0xf bank_mask:0xf\n\t"
        "v_fmac_f32_dpp %7, %9, %21 row_ror:14 row_mask:0xf bank_mask:0xf\n\t"
        "v_fmac_f32_dpp %0, %8, %22 row_ror:3 row_mask:0xf bank_mask:0xf\n\t"
        "v_fmac_f32_dpp %4, %9, %22 row_ror:3 row_mask:0xf bank_mask:0xf\n\t"
        "v_fmac_f32_dpp %1, %8, %23 row_ror:7 row_mask:0xf bank_mask:0xf\n\t"
        "v_fmac_f32_dpp %5, %9, %23 row_ror:7 row_mask:0xf bank_mask:0xf\n\t"
        "v_fmac_f32_dpp %2, %8, %24 row_ror:11 row_mask:0xf bank_mask:0xf\n\t"
        "v_fmac_f32_dpp %6, %9, %24 row_ror:11 row_mask:0xf bank_mask:0xf\n\t"
        "v_fmac_f32_dpp %3, %8, %25 row_ror:15 row_mask:0xf bank_mask:0xf\n\t"
        "v_fmac_f32_dpp %7, %9, %25 row_ror:15 row_mask:0xf bank_mask:0xf"
        : "+v"(a0A), "=&v"(a1A), "=&v"(a2A), "=&v"(a3A),
          "+v"(a0B), "=&v"(a1B), "=&v"(a2B), "=&v"(a3B)
        : "v"(hA), "v"(hB),
          "v"(Wp[0]), "v"(Wp[4]), "v"(Wp[8]), "v"(Wp[12]),
          "v"(Wp[1]), "v"(Wp[5]), "v"(Wp[9]), "v"(Wp[13]),
          "v"(Wp[2]), "v"(Wp[6]), "v"(Wp[10]), "v"(Wp[14]),
          "v"(Wp[3]), "v"(Wp[7]), "v"(Wp[11]), "v"(Wp[15]));
    float zA = (a0A + a1A) + (a2A + a3A);
    float zB = (a0B + a1B) + (a2B + a3B);

    float czA = __cosf(zA);
    float czB = __cosf(zB);
    // combined inclusive prefix product (DPP Hillis-Steele), A/B interleaved:
    // invalid lanes keep dst (BC=0) = multiplicative identity; the other
    // chain's instruction covers each DPP hazard slot.
    if constexpr (BASE == 0x110) {
        asm volatile(
            "s_nop 1\n\t"
            "v_mul_f32_dpp %0, %0, %0 row_shr:1 row_mask:0xf bank_mask:0xf\n\t"
            "v_mul_f32_dpp %1, %1, %1 row_shr:1 row_mask:0xf bank_mask:0xf\n\t"
            "v_mul_f32_dpp %0, %0, %0 row_shr:2 row_mask:0xf bank_mask:0xf\n\t"
            "v_mul_f32_dpp %1, %1, %1 row_shr:2 row_mask:0xf bank_mask:0xf\n\t"
            "v_mul_f32_dpp %0, %0, %0 row_shr:4 row_mask:0xf bank_mask:0xf\n\t"
            "v_mul_f32_dpp %1, %1, %1 row_shr:4 row_mask:0xf bank_mask:0xf\n\t"
            "v_mul_f32_dpp %0, %0, %0 row_shr:8 row_mask:0xf bank_mask:0xf\n\t"
            "v_mul_f32_dpp %1, %1, %1 row_shr:8 row_mask:0xf bank_mask:0xf"
            : "+v"(czA), "+v"(czB));
    } else {
        asm volatile(
            "s_nop 1\n\t"
            "v_mul_f32_dpp %0, %0, %0 row_shl:1 row_mask:0xf bank_mask:0xf\n\t"
            "v_mul_f32_dpp %1, %1, %1 row_shl:1 row_mask:0xf bank_mask:0xf\n\t"
            "v_mul_f32_dpp %0, %0, %0 row_shl:2 row_mask:0xf bank_mask:0xf\n\t"
            "v_mul_f32_dpp %1, %1, %1 row_shl:2 row_mask:0xf bank_mask:0xf\n\t"
            "v_mul_f32_dpp %0, %0, %0 row_shl:4 row_mask:0xf bank_mask:0xf\n\t"
            "v_mul_f32_dpp %1, %1, %1 row_shl:4 row_mask:0xf bank_mask:0xf\n\t"
            "v_mul_f32_dpp %0, %0, %0 row_shl:8 row_mask:0xf bank_mask:0xf\n\t"
            "v_mul_f32_dpp %1, %1, %1 row_shl:8 row_mask:0xf bank_mask:0xf"
            : "+v"(czA), "+v"(czB));
    }

    // gates: s = fmaf(ksc, 1/(1+2^(cz*kexp)), koff)
    float eA = __builtin_amdgcn_exp2f(czA * kexp);
    float eB = __builtin_amdgcn_exp2f(czB * kexp);
    float rrA = __builtin_amdgcn_rcpf(1.f + eA);
    float rrB = __builtin_amdgcn_rcpf(1.f + eB);
    float sA = fmaf(ksc, rrA, koff);
    float sB = fmaf(ksc, rrB, koff);

    float fvA, ivA, gvA, ovA, fvB, ivB, gvB, ovB;
    gex(sA, a_f, a_i, a_g, a_o, fvA, ivA, gvA, ovA);
    gex(sB, a_f, a_i, a_g, a_o, fvB, ivB, gvB, ovB);

    cA = fmaf(fvA, cA, ivA * gvA);
    cB = fmaf(fvB, cB, ivB * gvB);
    // tanh(c) = 2/(1+2^(-2c*log2e)) - 1
    float e2A = __builtin_amdgcn_exp2f(cA * -2.885390082f);
    float e2B = __builtin_amdgcn_exp2f(cB * -2.885390082f);
    float tcA = fmaf(2.f, __builtin_amdgcn_rcpf(1.f + e2A), -1.f);
    float tcB = fmaf(2.f, __builtin_amdgcn_rcpf(1.f + e2B), -1.f);
    hA = ovA * tcA;
    hB = ovB * tcB;

    if ((t & 3) == g) { hsA = hA; hsB = hB; }
    if ((t & 3) == 3) {
        out[(size_t)(t - 3 + g) * (BATCH * NQ) + (size_t)bA * NQ + n] = hsA;
        out[(size_t)(t - 3 + g) * (BATCH * NQ) + (size_t)bB * NQ + n] = hsB;
    }
}

// ---------------- fused per-wave main (2 batches / wave) ----------------
// MFMA A-row m <-> (batch = bA + (m>>3), t_local = m&7); 32 tiles of 8 steps.
// wfh/wfl[kt*4+nb][lane]: W fragments in LDS, built once (one barrier).
template <int BASE, typename InT>
__device__ __forceinline__ void fused_main(
    const InT* __restrict__ x, const InT* __restrict__ W,
    const InT* __restrict__ bv, const InT* __restrict__ th,
    float* __restrict__ out, int bA, int w, int lane,
    const float (&Wp)[16], float (*zt)[ZROW],
    bf16x8 (*wfh)[64], bf16x8 (*wfl)[64])
{
    const int m = lane & 15, quad = lane >> 4;
    const int g = quad, n = m;
    const int bB = bA + 1;
    const float kexp = (g == 2) ? -2.885390082f : -1.442695041f;
    const float ksc  = (g == 2) ? 2.f : 1.f;
    const float koff = (g == 2) ? -1.f : 0.f;
    const int a_f = n << 2, a_i = (16 + n) << 2, a_g = (32 + n) << 2, a_o = (48 + n) << 2;

    // ---- cooperative W-fragment build: wave w handles k-tile kt = w ----
    if constexpr (sizeof(InT) == 2) {
#pragma unroll
        for (int nb = 0; nb < 4; ++nb)
            wfh[w * 4 + nb][lane] = *(const bf16x8*)((const unsigned short*)W +
                                    (size_t)(nb * 16 + m) * DTOT + w * 32 + quad * 8);
    } else {
#pragma unroll
        for (int nb = 0; nb < 4; ++nb) {
            const float* p = (const float*)W + (size_t)(nb * 16 + m) * DTOT + w * 32 + quad * 8;
            bf16x8 ah, al;
#pragma unroll
            for (int j = 0; j < 8; ++j) {
                float wv = p[j];
                unsigned short hh = f2bf(wv);
                ah[j] = (short)hh;
                al[j] = (short)f2bf(wv - bf2f(hh));
            }
            wfh[w * 4 + nb][lane] = ah;
            wfl[w * 4 + nb][lane] = al;
        }
    }
    const float bias = ldval(bv + lane) + ldval(th + lane);
    __syncthreads();            // the ONLY barrier; wf* read-only afterwards

    // A-row m -> x row (t = tl*8 + (m&7), batch = bA + (m>>3))
    const InT* xbase = x + ((size_t)(m & 7) * BATCH + (size_t)(bA + (m >> 3))) * DIN + quad * 8;

    f32x4 rx[8]; bf16x8 rbx[4];
    auto LOAD = [&](int tl) {
        const InT* p = xbase + (size_t)tl * ((size_t)8 * BATCH * DIN);
#pragma unroll
        for (int kt = 0; kt < 4; ++kt) {
            if constexpr (sizeof(InT) == 2) {
                rbx[kt] = *(const bf16x8*)(p + kt * 32);
            } else {
                rx[2 * kt]     = *(const f32x4*)((const float*)p + kt * 32);
                rx[2 * kt + 1] = *(const f32x4*)((const float*)p + kt * 32 + 4);
            }
        }
    };
    auto PRODUCE = [&]() {
        f32x4 acc[4] = {};
#pragma unroll
        for (int kt = 0; kt < 4; ++kt) {
            if constexpr (sizeof(InT) == 2) {
#pragma unroll
                for (int nb = 0; nb < 4; ++nb)
                    acc[nb] = __builtin_amdgcn_mfma_f32_16x16x32_bf16(rbx[kt], wfh[kt * 4 + nb][lane], acc[nb], 0, 0, 0);
            } else {
                bf16x8 ah, al;
#pragma unroll
                for (int j = 0; j < 8; ++j) {
                    float xv = rx[2 * kt + (j >> 2)][j & 3];
                    unsigned short hh = f2bf(xv);
                    ah[j] = (short)hh;
                    al[j] = (short)f2bf(xv - bf2f(hh));
                }
#pragma unroll
                for (int nb = 0; nb < 4; ++nb)
                    acc[nb] = __builtin_amdgcn_mfma_f32_16x16x32_bf16(ah, wfh[kt * 4 + nb][lane], acc[nb], 0, 0, 0);
#pragma unroll
                for (int nb = 0; nb < 4; ++nb)
                    acc[nb] = __builtin_amdgcn_mfma_f32_16x16x32_bf16(al, wfh[kt * 4 + nb][lane], acc[nb], 0, 0, 0);
#pragma unroll
                for (int nb = 0; nb < 4; ++nb)
                    acc[nb] = __builtin_amdgcn_mfma_f32_16x16x32_bf16(ah, wfl[kt * 4 + nb][lane], acc[nb], 0, 0, 0);
            }
        }
        // z[row = quad*4+r][col = nb*16+m]; rows 0..7 = batch A t0..7, 8..15 = batch B
#pragma unroll
        for (int nb = 0; nb < 4; ++nb)
#pragma unroll
            for (int r = 0; r < 4; ++r)
                zt[quad * 4 + r][nb * 16 + m] = acc[nb][r];
    };

    float hA = 0.f, cA = 0.f, hsA = 0.f;
    float hB = 0.f, cB = 0.f, hsB = 0.f;

    LOAD(0);
    PRODUCE();
    LOAD(1);

#pragma unroll 1
    for (int tl = 0; tl < NTILE; ++tl) {
        const int t0 = tl * 8;
        float zrA[8], zrB[8];
#pragma unroll
        for (int j = 0; j < 8; ++j) zrA[j] = zt[j][lane] + bias;       // drain before overwrite
#pragma unroll
        for (int j = 0; j < 8; ++j) zrB[j] = zt[8 + j][lane] + bias;
        if (tl < NTILE - 1) PRODUCE();
        if (tl < NTILE - 2) LOAD(tl + 2);
#pragma unroll
        for (int j = 0; j < 8; ++j)
            qstep2<BASE>(t0 + j, g, n, zrA[j], zrB[j], Wp,
                         hA, cA, hsA, bA, hB, cB, hsB, bB,
                         kexp, ksc, koff, a_f, a_i, a_g, a_o, out);
    }

    if (g == 0) {
        out[(size_t)T_STEPS * BATCH * NQ + (size_t)bA * NQ + n] = hA;                      // hx
        out[(size_t)T_STEPS * BATCH * NQ + (size_t)BATCH * NQ + (size_t)bA * NQ + n] = cA; // cx
        out[(size_t)T_STEPS * BATCH * NQ + (size_t)bB * NQ + n] = hB;
        out[(size_t)T_STEPS * BATCH * NQ + (size_t)BATCH * NQ + (size_t)bB * NQ + n] = cB;
    }
}

__global__ __launch_bounds__(256, 1) void qlstm_fused(
    const void* __restrict__ x_, const void* __restrict__ W_,
    const void* __restrict__ b_, const void* __restrict__ th_,
    float* __restrict__ out)
{
    __shared__ float  zw[4][16][ZROW];      // 16.5 KiB: per-wave z tiles
    __shared__ bf16x8 wfh[16][64];          // 16 KiB: W hi fragments (shared)
    __shared__ bf16x8 wfl[16][64];          // 16 KiB: W lo fragments (fp32 path)

    const int lane = threadIdx.x & 63;
    const int w    = threadIdx.x >> 6;
    const int bA   = (blockIdx.x * 4 + w) * 2;
    const int n    = lane & 15;

    const int isbf = __builtin_amdgcn_readfirstlane(detect_bf16((const unsigned int*)x_, lane));

    // runtime probe of DPP row_ror direction (wave-uniform)
    int pr  = __builtin_amdgcn_update_dpp(0, lane, 0x121, 0xF, 0xF, false);
    int p0r = __shfl(pr, 0, 64);
    const int d = (p0r == 1) ? 1 : 15;

    float Wp[16];
    if (isbf) {
        const unsigned short* W = (const unsigned short*)W_;
#pragma unroll
        for (int k = 0; k < 16; ++k)
            Wp[k] = bf2f(W[(size_t)lane * DTOT + DIN + ((n + k * d) & 15)]);
    } else {
        const float* W = (const float*)W_;
#pragma unroll
        for (int k = 0; k < 16; ++k)
            Wp[k] = W[(size_t)lane * DTOT + DIN + ((n + k * d) & 15)];
    }

    // runtime probe of DPP row_shr direction (wave-uniform) for the prefix product
    int probe = __builtin_amdgcn_update_dpp(999, lane, 0x111, 0xF, 0xF, false);
    int p2 = __shfl(probe, 2, 64);

    if (isbf) {
        if (p2 == 1) fused_main<0x110, unsigned short>((const unsigned short*)x_, (const unsigned short*)W_,
                                                       (const unsigned short*)b_, (const unsigned short*)th_,
                                                       out, bA, w, lane, Wp, zw[w], wfh, wfl);
        else         fused_main<0x100, unsigned short>((const unsigned short*)x_, (const unsigned short*)W_,
                                                       (const unsigned short*)b_, (const unsigned short*)th_,
                                                       out, bA, w, lane, Wp, zw[w], wfh, wfl);
    } else {
        if (p2 == 1) fused_main<0x110, float>((const float*)x_, (const float*)W_,
                                              (const float*)b_, (const float*)th_,
                                              out, bA, w, lane, Wp, zw[w], wfh, wfl);
        else         fused_main<0x100, float>((const float*)x_, (const float*)W_,
                                              (const float*)b_, (const float*)th_,
                                              out, bA, w, lane, Wp, zw[w], wfh, wfl);
    }
}

extern "C" void kernel_launch(void* const* d_in, const int* in_sizes, int n_in,
                              void* d_out, int out_size, void* d_ws, size_t ws_size,
                              hipStream_t stream) {
    const void* x  = d_in[0];
    const void* W  = d_in[1];
    const void* bv = d_in[2];
    const void* th = d_in[3];
    (void)d_ws; (void)ws_size;
    qlstm_fused<<<BATCH / 8, 256, 0, stream>>>(x, W, bv, th, (float*)d_out);
}

// Round 14
// 368.828 us; speedup vs baseline: 1.1639x; 1.0251x over previous
//
#include <hip/hip_runtime.h>
#include <hip/hip_bf16.h>
#include <stdint.h>

// QLSTM: T=256, B=2048, DIN=128, NQ=16, 4 gates. fp32 inputs, fp32 outputs.
// R18: R17 resubmit (compile fix: ext_vector elements can't bind to refs ->
// split2 returns a uint2-style pair by value). Content identical to R17:
// R16 (best, 378.1us) + hardware bf16 conversion in the fp32 staging path.
//   - PRODUCE's software RNE split (~28 inst/pair) -> v_cvt_pk_bf16_f32
//     (HW RNE): {cvt_pk, shl, and, 2 sub, cvt_pk} = 6 inst/pair.
//     ~44 inst/step-pair removed ~= 9us predicted at R16's measured
//     0.2us/inst rate.
//   - RNE == RNE for finite inputs -> bit-identical z -> absmax must stay
//     exactly 0.00390625. Everything else byte-for-byte R16.

#define T_STEPS 256
#define BATCH   2048
#define DIN     128
#define NQ      16
#define DTOT    144
#define NTILE   32          // 32 tiles of 8 timesteps
#define ZROW    66          // padded z row (floats)

typedef __attribute__((ext_vector_type(8))) short bf16x8;
typedef __attribute__((ext_vector_type(4))) float f32x4;
typedef __attribute__((ext_vector_type(4))) unsigned int u32x4;

__device__ __forceinline__ float bf2f(unsigned short u) {
    union { unsigned int i; float f; } v; v.i = ((unsigned int)u) << 16; return v.f;
}
__device__ __forceinline__ unsigned short f2bf(float f) {
    union { float f; unsigned int i; } v; v.f = f;
    unsigned int i = v.i;
    unsigned int r = i + 0x7fffu + ((i >> 16) & 1u);   // round-nearest-even
    return (unsigned short)(r >> 16);
}
__device__ __forceinline__ float ldval(const float* p) { return *p; }
__device__ __forceinline__ float ldval(const unsigned short* p) { return bf2f(*p); }

// HW packed f32->bf16 (RNE), dst.lo = cvt(a), dst.hi = cvt(b). Pure asm (no
// volatile) so the scheduler stays free.
__device__ __forceinline__ unsigned int cvt_pk_bf16(float a, float b) {
    unsigned int r;
    asm("v_cvt_pk_bf16_f32 %0, %1, %2" : "=v"(r) : "v"(a), "v"(b));
    return r;
}
struct bfpair { unsigned int hw, lw; };
// hi/lo split of two f32 into packed bf16 words: hw = hi parts, lw = lo parts.
__device__ __forceinline__ bfpair split2(float x0, float x1) {
    bfpair r;
    r.hw = cvt_pk_bf16(x0, x1);
    float r0 = __builtin_bit_cast(float, r.hw << 16);
    float r1 = __builtin_bit_cast(float, r.hw & 0xffff0000u);
    r.lw = cvt_pk_bf16(x0 - r0, x1 - r1);
    return r;
}

// ---------------- per-wave dtype detector (bf16=1, fp32=0), wave-uniform ----------------
__device__ __forceinline__ int detect_bf16(const unsigned int* __restrict__ xw, int lane) {
    int cnt = 0;
#pragma unroll
    for (int i = 0; i < 4; ++i) {
        unsigned int w = xw[lane + i * 64];
        unsigned int e = (w >> 7) & 0xFFu;
        cnt += (e >= 100u && e <= 140u) ? 1 : 0;
    }
#pragma unroll
    for (int d = 32; d > 0; d >>= 1) cnt += __shfl_down(cnt, d, 64);
    int tot = __shfl(cnt, 0, 64);
    return (tot >= 140) ? 1 : 0;
}

// ---------------- gate exchange: s(row g) -> f/i/g/o at qubit n (exact) ----------------
__device__ __forceinline__ void gex(float s,
                                    int a_f, int a_i, int a_g, int a_o,
                                    float& fv, float& iv, float& gv, float& ov)
{
    int si = __builtin_bit_cast(int, s);
    fv = __builtin_bit_cast(float, __builtin_amdgcn_ds_bpermute(a_f, si));
    iv = __builtin_bit_cast(float, __builtin_amdgcn_ds_bpermute(a_i, si));
    gv = __builtin_bit_cast(float, __builtin_amdgcn_ds_bpermute(a_g, si));
    ov = __builtin_bit_cast(float, __builtin_amdgcn_ds_bpermute(a_o, si));
}

// ---------------- one recurrence step for TWO batches ----------------
template <int BASE>
__device__ __forceinline__ void qstep2(int t, int g, int n,
                                       float curA, float curB, const float (&Wp)[16],
                                       float& hA, float& cA, float& hsA, int bA,
                                       float& hB, float& cB, float& hsB, int bB,
                                       float kexp, float ksc, float koff,
                                       int a_f, int a_i, int a_g, int a_o,
                                       float* __restrict__ out)
{
    // combined h-dot: A/B chains interleaved; accumulator reuse distance 8 inst.
    float a0A = curA, a1A, a2A, a3A;
    float a0B = curB, a1B, a2B, a3B;
    asm volatile(
        "s_nop 1\n\t"
        "v_fmac_f32 %0, %8, %10\n\t"
        "v_fmac_f32 %4, %9, %10\n\t"
        "v_mul_f32_dpp %1, %8, %11 row_ror:4 row_mask:0xf bank_mask:0xf\n\t"
        "v_mul_f32_dpp %5, %9, %11 row_ror:4 row_mask:0xf bank_mask:0xf\n\t"
        "v_mul_f32_dpp %2, %8, %12 row_ror:8 row_mask:0xf bank_mask:0xf\n\t"
        "v_mul_f32_dpp %6, %9, %12 row_ror:8 row_mask:0xf bank_mask:0xf\n\t"
        "v_mul_f32_dpp %3, %8, %13 row_ror:12 row_mask:0xf bank_mask:0xf\n\t"
        "v_mul_f32_dpp %7, %9, %13 row_ror:12 row_mask:0xf bank_mask:0xf\n\t"
        "v_fmac_f32_dpp %0, %8, %14 row_ror:1 row_mask:0xf bank_mask:0xf\n\t"
        "v_fmac_f32_dpp %4, %9, %14 row_ror:1 row_mask:0xf bank_mask:0xf\n\t"
        "v_fmac_f32_dpp %1, %8, %15 row_ror:5 row_mask:0xf bank_mask:0xf\n\t"
        "v_fmac_f32_dpp %5, %9, %15 row_ror:5 row_mask:0xf bank_mask:0xf\n\t"
        "v_fmac_f32_dpp %2, %8, %16 row_ror:9 row_mask:0xf bank_mask:0xf\n\t"
        "v_fmac_f32_dpp %6, %9, %16 row_ror:9 row_mask:0xf bank_mask:0xf\n\t"
        "v_fmac_f32_dpp %3, %8, %17 row_ror:13 row_mask:0xf bank_mask:0xf\n\t"
        "v_fmac_f32_dpp %7, %9, %17 row_ror:13 row_mask:0xf bank_mask:0xf\n\t"
        "v_fmac_f32_dpp %0, %8, %18 row_ror:2 row_mask:0xf bank_mask:0xf\n\t"
        "v_fmac_f32_dpp %4, %9, %18 row_ror:2 row_mask:0xf bank_mask:0xf\n\t"
        "v_fmac_f32_dpp %1, %8, %19 row_ror:6 row_mask:0xf bank_mask:0xf\n\t"
        "v_fmac_f32_dpp %5, %9, %19 row_ror:6 row_mask:0xf bank_mask:0xf\n\t"
        "v_fmac_f32_dpp %2, %8, %20 row_ror:10 row_mask:0xf bank_mask:0xf\n\t"
        "v_fmac_f32_dpp %6, %9, %20 row_ror:10 row_mask:0xf bank_mask:0xf\n\t"
        "v_fmac_f32_dpp %3, %8, %21 row_ror:14 row_mask:0xf bank_mask:0xf\n\t"
        "v_fmac_f32_dpp %7, %9, %21 row_ror:14 row_mask:0xf bank_mask:0xf\n\t"
        "v_fmac_f32_dpp %0, %8, %22 row_ror:3 row_mask:0xf bank_mask:0xf\n\t"
        "v_fmac_f32_dpp %4, %9, %22 row_ror:3 row_mask:0xf bank_mask:0xf\n\t"
        "v_fmac_f32_dpp %1, %8, %23 row_ror:7 row_mask:0xf bank_mask:0xf\n\t"
        "v_fmac_f32_dpp %5, %9, %23 row_ror:7 row_mask:0xf bank_mask:0xf\n\t"
        "v_fmac_f32_dpp %2, %8, %24 row_ror:11 row_mask:0xf bank_mask:0xf\n\t"
        "v_fmac_f32_dpp %6, %9, %24 row_ror:11 row_mask:0xf bank_mask:0xf\n\t"
        "v_fmac_f32_dpp %3, %8, %25 row_ror:15 row_mask:0xf bank_mask:0xf\n\t"
        "v_fmac_f32_dpp %7, %9, %25 row_ror:15 row_mask:0xf bank_mask:0xf"
        : "+v"(a0A), "=&v"(a1A), "=&v"(a2A), "=&v"(a3A),
          "+v"(a0B), "=&v"(a1B), "=&v"(a2B), "=&v"(a3B)
        : "v"(hA), "v"(hB),
          "v"(Wp[0]), "v"(Wp[4]), "v"(Wp[8]), "v"(Wp[12]),
          "v"(Wp[1]), "v"(Wp[5]), "v"(Wp[9]), "v"(Wp[13]),
          "v"(Wp[2]), "v"(Wp[6]), "v"(Wp[10]), "v"(Wp[14]),
          "v"(Wp[3]), "v"(Wp[7]), "v"(Wp[11]), "v"(Wp[15]));
    float zA = (a0A + a1A) + (a2A + a3A);
    float zB = (a0B + a1B) + (a2B + a3B);

    float czA = __cosf(zA);
    float czB = __cosf(zB);
    // combined inclusive prefix product (DPP Hillis-Steele), A/B interleaved:
    // invalid lanes keep dst (BC=0) = multiplicative identity; the other
    // chain's instruction covers each DPP hazard slot.
    if constexpr (BASE == 0x110) {
        asm volatile(
            "s_nop 1\n\t"
            "v_mul_f32_dpp %0, %0, %0 row_shr:1 row_mask:0xf bank_mask:0xf\n\t"
            "v_mul_f32_dpp %1, %1, %1 row_shr:1 row_mask:0xf bank_mask:0xf\n\t"
            "v_mul_f32_dpp %0, %0, %0 row_shr:2 row_mask:0xf bank_mask:0xf\n\t"
            "v_mul_f32_dpp %1, %1, %1 row_shr:2 row_mask:0xf bank_mask:0xf\n\t"
            "v_mul_f32_dpp %0, %0, %0 row_shr:4 row_mask:0xf bank_mask:0xf\n\t"
            "v_mul_f32_dpp %1, %1, %1 row_shr:4 row_mask:0xf bank_mask:0xf\n\t"
            "v_mul_f32_dpp %0, %0, %0 row_shr:8 row_mask:0xf bank_mask:0xf\n\t"
            "v_mul_f32_dpp %1, %1, %1 row_shr:8 row_mask:0xf bank_mask:0xf"
            : "+v"(czA), "+v"(czB));
    } else {
        asm volatile(
            "s_nop 1\n\t"
            "v_mul_f32_dpp %0, %0, %0 row_shl:1 row_mask:0xf bank_mask:0xf\n\t"
            "v_mul_f32_dpp %1, %1, %1 row_shl:1 row_mask:0xf bank_mask:0xf\n\t"
            "v_mul_f32_dpp %0, %0, %0 row_shl:2 row_mask:0xf bank_mask:0xf\n\t"
            "v_mul_f32_dpp %1, %1, %1 row_shl:2 row_mask:0xf bank_mask:0xf\n\t"
            "v_mul_f32_dpp %0, %0, %0 row_shl:4 row_mask:0xf bank_mask:0xf\n\t"
            "v_mul_f32_dpp %1, %1, %1 row_shl:4 row_mask:0xf bank_mask:0xf\n\t"
            "v_mul_f32_dpp %0, %0, %0 row_shl:8 row_mask:0xf bank_mask:0xf\n\t"
            "v_mul_f32_dpp %1, %1, %1 row_shl:8 row_mask:0xf bank_mask:0xf"
            : "+v"(czA), "+v"(czB));
    }

    // gates: s = fmaf(ksc, 1/(1+2^(cz*kexp)), koff)
    float eA = __builtin_amdgcn_exp2f(czA * kexp);
    float eB = __builtin_amdgcn_exp2f(czB * kexp);
    float rrA = __builtin_amdgcn_rcpf(1.f + eA);
    float rrB = __builtin_amdgcn_rcpf(1.f + eB);
    float sA = fmaf(ksc, rrA, koff);
    float sB = fmaf(ksc, rrB, koff);

    float fvA, ivA, gvA, ovA, fvB, ivB, gvB, ovB;
    gex(sA, a_f, a_i, a_g, a_o, fvA, ivA, gvA, ovA);
    gex(sB, a_f, a_i, a_g, a_o, fvB, ivB, gvB, ovB);

    cA = fmaf(fvA, cA, ivA * gvA);
    cB = fmaf(fvB, cB, ivB * gvB);
    // tanh(c) = 2/(1+2^(-2c*log2e)) - 1
    float e2A = __builtin_amdgcn_exp2f(cA * -2.885390082f);
    float e2B = __builtin_amdgcn_exp2f(cB * -2.885390082f);
    float tcA = fmaf(2.f, __builtin_amdgcn_rcpf(1.f + e2A), -1.f);
    float tcB = fmaf(2.f, __builtin_amdgcn_rcpf(1.f + e2B), -1.f);
    hA = ovA * tcA;
    hB = ovB * tcB;

    if ((t & 3) == g) { hsA = hA; hsB = hB; }
    if ((t & 3) == 3) {
        out[(size_t)(t - 3 + g) * (BATCH * NQ) + (size_t)bA * NQ + n] = hsA;
        out[(size_t)(t - 3 + g) * (BATCH * NQ) + (size_t)bB * NQ + n] = hsB;
    }
}

// ---------------- fused per-wave main (2 batches / wave) ----------------
// MFMA A-row m <-> (batch = bA + (m>>3), t_local = m&7); 32 tiles of 8 steps.
// wfh/wfl[kt*4+nb][lane]: W fragments in LDS, built once (one barrier).
template <int BASE, typename InT>
__device__ __forceinline__ void fused_main(
    const InT* __restrict__ x, const InT* __restrict__ W,
    const InT* __restrict__ bv, const InT* __restrict__ th,
    float* __restrict__ out, int bA, int w, int lane,
    const float (&Wp)[16], float (*zt)[ZROW],
    bf16x8 (*wfh)[64], bf16x8 (*wfl)[64])
{
    const int m = lane & 15, quad = lane >> 4;
    const int g = quad, n = m;
    const int bB = bA + 1;
    const float kexp = (g == 2) ? -2.885390082f : -1.442695041f;
    const float ksc  = (g == 2) ? 2.f : 1.f;
    const float koff = (g == 2) ? -1.f : 0.f;
    const int a_f = n << 2, a_i = (16 + n) << 2, a_g = (32 + n) << 2, a_o = (48 + n) << 2;

    // ---- cooperative W-fragment build: wave w handles k-tile kt = w ----
    if constexpr (sizeof(InT) == 2) {
#pragma unroll
        for (int nb = 0; nb < 4; ++nb)
            wfh[w * 4 + nb][lane] = *(const bf16x8*)((const unsigned short*)W +
                                    (size_t)(nb * 16 + m) * DTOT + w * 32 + quad * 8);
    } else {
#pragma unroll
        for (int nb = 0; nb < 4; ++nb) {
            const float* p = (const float*)W + (size_t)(nb * 16 + m) * DTOT + w * 32 + quad * 8;
            u32x4 hw_, lw_;
#pragma unroll
            for (int q = 0; q < 4; ++q) {
                bfpair pr = split2(p[2 * q], p[2 * q + 1]);
                hw_[q] = pr.hw;
                lw_[q] = pr.lw;
            }
            wfh[w * 4 + nb][lane] = __builtin_bit_cast(bf16x8, hw_);
            wfl[w * 4 + nb][lane] = __builtin_bit_cast(bf16x8, lw_);
        }
    }
    const float bias = ldval(bv + lane) + ldval(th + lane);
    __syncthreads();            // the ONLY barrier; wf* read-only afterwards

    // A-row m -> x row (t = tl*8 + (m&7), batch = bA + (m>>3))
    const InT* xbase = x + ((size_t)(m & 7) * BATCH + (size_t)(bA + (m >> 3))) * DIN + quad * 8;

    f32x4 rx[8]; bf16x8 rbx[4];
    auto LOAD = [&](int tl) {
        const InT* p = xbase + (size_t)tl * ((size_t)8 * BATCH * DIN);
#pragma unroll
        for (int kt = 0; kt < 4; ++kt) {
            if constexpr (sizeof(InT) == 2) {
                rbx[kt] = *(const bf16x8*)(p + kt * 32);
            } else {
                rx[2 * kt]     = *(const f32x4*)((const float*)p + kt * 32);
                rx[2 * kt + 1] = *(const f32x4*)((const float*)p + kt * 32 + 4);
            }
        }
    };
    auto PRODUCE = [&]() {
        f32x4 acc[4] = {};
#pragma unroll
        for (int kt = 0; kt < 4; ++kt) {
            if constexpr (sizeof(InT) == 2) {
#pragma unroll
                for (int nb = 0; nb < 4; ++nb)
                    acc[nb] = __builtin_amdgcn_mfma_f32_16x16x32_bf16(rbx[kt], wfh[kt * 4 + nb][lane], acc[nb], 0, 0, 0);
            } else {
                // HW bf16 hi/lo split: 6 inst per element-pair (was ~28 with
                // the software RNE bit-trick). RNE == RNE -> bit-identical.
                u32x4 hw_, lw_;
#pragma unroll
                for (int q = 0; q < 4; ++q) {
                    float x0 = rx[2 * kt + (q >> 1)][(q & 1) * 2];
                    float x1 = rx[2 * kt + (q >> 1)][(q & 1) * 2 + 1];
                    bfpair pr = split2(x0, x1);
                    hw_[q] = pr.hw;
                    lw_[q] = pr.lw;
                }
                bf16x8 ah = __builtin_bit_cast(bf16x8, hw_);
                bf16x8 al = __builtin_bit_cast(bf16x8, lw_);
#pragma unroll
                for (int nb = 0; nb < 4; ++nb)
                    acc[nb] = __builtin_amdgcn_mfma_f32_16x16x32_bf16(ah, wfh[kt * 4 + nb][lane], acc[nb], 0, 0, 0);
#pragma unroll
                for (int nb = 0; nb < 4; ++nb)
                    acc[nb] = __builtin_amdgcn_mfma_f32_16x16x32_bf16(al, wfh[kt * 4 + nb][lane], acc[nb], 0, 0, 0);
#pragma unroll
                for (int nb = 0; nb < 4; ++nb)
                    acc[nb] = __builtin_amdgcn_mfma_f32_16x16x32_bf16(ah, wfl[kt * 4 + nb][lane], acc[nb], 0, 0, 0);
            }
        }
        // z[row = quad*4+r][col = nb*16+m]; rows 0..7 = batch A t0..7, 8..15 = batch B
#pragma unroll
        for (int nb = 0; nb < 4; ++nb)
#pragma unroll
            for (int r = 0; r < 4; ++r)
                zt[quad * 4 + r][nb * 16 + m] = acc[nb][r];
    };

    float hA = 0.f, cA = 0.f, hsA = 0.f;
    float hB = 0.f, cB = 0.f, hsB = 0.f;

    LOAD(0);
    PRODUCE();
    LOAD(1);

#pragma unroll 1
    for (int tl = 0; tl < NTILE; ++tl) {
        const int t0 = tl * 8;
        float zrA[8], zrB[8];
#pragma unroll
        for (int j = 0; j < 8; ++j) zrA[j] = zt[j][lane] + bias;       // drain before overwrite
#pragma unroll
        for (int j = 0; j < 8; ++j) zrB[j] = zt[8 + j][lane] + bias;
        if (tl < NTILE - 1) PRODUCE();
        if (tl < NTILE - 2) LOAD(tl + 2);
#pragma unroll
        for (int j = 0; j < 8; ++j)
            qstep2<BASE>(t0 + j, g, n, zrA[j], zrB[j], Wp,
                         hA, cA, hsA, bA, hB, cB, hsB, bB,
                         kexp, ksc, koff, a_f, a_i, a_g, a_o, out);
    }

    if (g == 0) {
        out[(size_t)T_STEPS * BATCH * NQ + (size_t)bA * NQ + n] = hA;                      // hx
        out[(size_t)T_STEPS * BATCH * NQ + (size_t)BATCH * NQ + (size_t)bA * NQ + n] = cA; // cx
        out[(size_t)T_STEPS * BATCH * NQ + (size_t)bB * NQ + n] = hB;
        out[(size_t)T_STEPS * BATCH * NQ + (size_t)BATCH * NQ + (size_t)bB * NQ + n] = cB;
    }
}

__global__ __launch_bounds__(256, 1) void qlstm_fused(
    const void* __restrict__ x_, const void* __restrict__ W_,
    const void* __restrict__ b_, const void* __restrict__ th_,
    float* __restrict__ out)
{
    __shared__ float  zw[4][16][ZROW];      // 16.5 KiB: per-wave z tiles
    __shared__ bf16x8 wfh[16][64];          // 16 KiB: W hi fragments (shared)
    __shared__ bf16x8 wfl[16][64];          // 16 KiB: W lo fragments (fp32 path)

    const int lane = threadIdx.x & 63;
    const int w    = threadIdx.x >> 6;
    const int bA   = (blockIdx.x * 4 + w) * 2;
    const int n    = lane & 15;

    const int isbf = __builtin_amdgcn_readfirstlane(detect_bf16((const unsigned int*)x_, lane));

    // runtime probe of DPP row_ror direction (wave-uniform)
    int pr  = __builtin_amdgcn_update_dpp(0, lane, 0x121, 0xF, 0xF, false);
    int p0r = __shfl(pr, 0, 64);
    const int d = (p0r == 1) ? 1 : 15;

    float Wp[16];
    if (isbf) {
        const unsigned short* W = (const unsigned short*)W_;
#pragma unroll
        for (int k = 0; k < 16; ++k)
            Wp[k] = bf2f(W[(size_t)lane * DTOT + DIN + ((n + k * d) & 15)]);
    } else {
        const float* W = (const float*)W_;
#pragma unroll
        for (int k = 0; k < 16; ++k)
            Wp[k] = W[(size_t)lane * DTOT + DIN + ((n + k * d) & 15)];
    }

    // runtime probe of DPP row_shr direction (wave-uniform) for the prefix product
    int probe = __builtin_amdgcn_update_dpp(999, lane, 0x111, 0xF, 0xF, false);
    int p2 = __shfl(probe, 2, 64);

    if (isbf) {
        if (p2 == 1) fused_main<0x110, unsigned short>((const unsigned short*)x_, (const unsigned short*)W_,
                                                       (const unsigned short*)b_, (const unsigned short*)th_,
                                                       out, bA, w, lane, Wp, zw[w], wfh, wfl);
        else         fused_main<0x100, unsigned short>((const unsigned short*)x_, (const unsigned short*)W_,
                                                       (const unsigned short*)b_, (const unsigned short*)th_,
                                                       out, bA, w, lane, Wp, zw[w], wfh, wfl);
    } else {
        if (p2 == 1) fused_main<0x110, float>((const float*)x_, (const float*)W_,
                                              (const float*)b_, (const float*)th_,
                                              out, bA, w, lane, Wp, zw[w], wfh, wfl);
        else         fused_main<0x100, float>((const float*)x_, (const float*)W_,
                                              (const float*)b_, (const float*)th_,
                                              out, bA, w, lane, Wp, zw[w], wfh, wfl);
    }
}

extern "C" void kernel_launch(void* const* d_in, const int* in_sizes, int n_in,
                              void* d_out, int out_size, void* d_ws, size_t ws_size,
                              hipStream_t stream) {
    const void* x  = d_in[0];
    const void* W  = d_in[1];
    const void* bv = d_in[2];
    const void* th = d_in[3];
    (void)d_ws; (void)ws_size;
    qlstm_fused<<<BATCH / 8, 256, 0, stream>>>(x, W, bv, th, (float*)d_out);
}